// Round 1
// baseline (720.144 us; speedup 1.0000x reference)
//
#include <hip/hip_runtime.h>
#include <math.h>

// Problem constants
#define NTOK 8192
#define DDIM 1024
#define NEXP 8
#define HDIM 256
#define TOPK 2
#define CAP  (NTOK * TOPK + NEXP * 64)   // 16896 slots (exact total 16384 + per-expert pad)
#define NTILES (CAP / 64)                // 264 row tiles (worst case)

// Workspace layout (bytes). Total ~34.9 MB.
#define CNT_OFF   0                      // 8 int
#define CUR_OFF   32                     // 8 int
#define TOFF_OFF  64                     // 9 int
#define TOP2E_OFF 256                    // N*2 int  = 65536 B
#define TOP2G_OFF (TOP2E_OFF + NTOK * 2 * 4)            // N*2 float
#define TOK_OFF   (TOP2G_OFF + NTOK * 2 * 4)            // CAP int
#define GAT_OFF   (TOK_OFF + CAP * 4)                   // CAP float
#define H1_OFF    (GAT_OFF + CAP * 4)                   // CAP*H float = 17.3 MB
#define H2_OFF    (H1_OFF + (size_t)CAP * HDIM * 4)     // CAP*H float = 17.3 MB

// ---------------------------------------------------------------------------
// Gating: one wave (64 lanes) per token. Coalesced x row read; Wg (32 KB) is
// L1/L2 resident. Softmax over 8 experts, pick top-2 (strict > keeps lowest
// index on ties, matching jax.lax.top_k).
// ---------------------------------------------------------------------------
__global__ __launch_bounds__(256) void gate_topk(
    const float* __restrict__ x, const float* __restrict__ Wg,
    const float* __restrict__ bg, int* __restrict__ top2e,
    float* __restrict__ top2g, int* __restrict__ counts)
{
    const int n = blockIdx.x * 4 + (threadIdx.x >> 6);
    const int lane = threadIdx.x & 63;
    const float* xr = x + (size_t)n * DDIM;

    float acc[NEXP];
#pragma unroll
    for (int e = 0; e < NEXP; ++e) acc[e] = 0.f;

#pragma unroll 4
    for (int it = 0; it < DDIM / 64; ++it) {
        const int d = it * 64 + lane;
        const float xv = xr[d];
        const float* wr = Wg + (size_t)d * NEXP;
        const float4 w0 = *(const float4*)wr;
        const float4 w1 = *(const float4*)(wr + 4);
        acc[0] = fmaf(xv, w0.x, acc[0]); acc[1] = fmaf(xv, w0.y, acc[1]);
        acc[2] = fmaf(xv, w0.z, acc[2]); acc[3] = fmaf(xv, w0.w, acc[3]);
        acc[4] = fmaf(xv, w1.x, acc[4]); acc[5] = fmaf(xv, w1.y, acc[5]);
        acc[6] = fmaf(xv, w1.z, acc[6]); acc[7] = fmaf(xv, w1.w, acc[7]);
    }

#pragma unroll
    for (int off = 32; off > 0; off >>= 1) {
#pragma unroll
        for (int e = 0; e < NEXP; ++e) acc[e] += __shfl_down(acc[e], off, 64);
    }

    if (lane == 0) {
        float v[NEXP], mx = -1e30f;
#pragma unroll
        for (int e = 0; e < NEXP; ++e) { v[e] = acc[e] + bg[e]; mx = fmaxf(mx, v[e]); }
        float p[NEXP], s = 0.f;
#pragma unroll
        for (int e = 0; e < NEXP; ++e) { p[e] = expf(v[e] - mx); s += p[e]; }
        const float inv = 1.f / s;
#pragma unroll
        for (int e = 0; e < NEXP; ++e) p[e] *= inv;

        int i0 = 0;
#pragma unroll
        for (int e = 1; e < NEXP; ++e) if (p[e] > p[i0]) i0 = e;
        int i1 = (i0 == 0) ? 1 : 0;
#pragma unroll
        for (int e = 0; e < NEXP; ++e) if (e != i0 && p[e] > p[i1]) i1 = e;

        top2e[n * 2 + 0] = i0;  top2e[n * 2 + 1] = i1;
        top2g[n * 2 + 0] = p[i0]; top2g[n * 2 + 1] = p[i1];
        atomicAdd(&counts[i0], 1);
        atomicAdd(&counts[i1], 1);
    }
}

// Padded prefix sum: each expert's slot range starts at a multiple of 64 so a
// 64-row GEMM tile never spans two experts. Also zero the scatter cursors.
__global__ void make_offsets(const int* __restrict__ counts,
                             int* __restrict__ toff, int* __restrict__ cursor)
{
    if (threadIdx.x == 0 && blockIdx.x == 0) {
        int acc = 0;
#pragma unroll
        for (int e = 0; e < NEXP; ++e) {
            toff[e] = acc;
            acc += (counts[e] + 63) & ~63;
            cursor[e] = 0;
        }
        toff[NEXP] = acc;
    }
}

__global__ __launch_bounds__(256) void scatter(
    const int* __restrict__ top2e, const float* __restrict__ top2g,
    const int* __restrict__ toff, int* __restrict__ cursor,
    int* __restrict__ tok, float* __restrict__ gat)
{
    const int n = blockIdx.x * blockDim.x + threadIdx.x;
    if (n >= NTOK) return;
#pragma unroll
    for (int k = 0; k < TOPK; ++k) {
        const int e = top2e[n * 2 + k];
        const int pos = atomicAdd(&cursor[e], 1);
        const int slot = toff[e] + pos;
        tok[slot] = n;
        gat[slot] = top2g[n * 2 + k];
    }
}

// ---------------------------------------------------------------------------
// Grouped expert GEMM. BM=BN=64, BK=16, 256 threads, 4x4 micro-tile per
// thread. K-major LDS tiles with +4 padding; both operands read as float4.
// GATHER: A rows gathered from x via tok[] (padding slots -> zero rows).
// FINAL:  epilogue relu(acc+b)*gate, atomicAdd into d_out (exactly 2 adds per
//         output element onto 0 -> commutative -> bit-deterministic).
// ---------------------------------------------------------------------------
template<int KDIM, int NCOL, bool GATHER, bool FINAL>
__global__ __launch_bounds__(256) void expert_gemm(
    const float* __restrict__ Ain, const float* __restrict__ Wall,
    const float* __restrict__ ball, const int* __restrict__ toff,
    const int* __restrict__ tok, const float* __restrict__ gat,
    float* __restrict__ Out)
{
    __shared__ float As[16][68];
    __shared__ float Bs[16][68];

    const int slot0 = blockIdx.x * 64;
    if (slot0 >= toff[NEXP]) return;
    int e = 0;
    while (toff[e + 1] <= slot0) ++e;

    const float* W = Wall + (size_t)e * KDIM * NCOL;
    const int col0 = blockIdx.y * 64;
    const int tid = threadIdx.x;
    const int tx = tid & 15, ty = tid >> 4;      // micro-tile coords
    const int arow = tid >> 2, akq = tid & 3;    // A loader: row 0..63, k-quad 0..3
    const int bk = tid >> 4, bcq = tid & 15;     // B loader: k-row 0..15, col-quad 0..15

    const float* aptr;
    if (GATHER) {
        const int t = tok[slot0 + arow];
        aptr = (t >= 0) ? (Ain + (size_t)t * KDIM + akq * 4) : nullptr;
    } else {
        aptr = Ain + (size_t)(slot0 + arow) * KDIM + akq * 4;
    }
    const float* bptr = W + (size_t)bk * NCOL + col0 + bcq * 4;

    float acc[4][4];
#pragma unroll
    for (int i = 0; i < 4; ++i)
#pragma unroll
        for (int j = 0; j < 4; ++j) acc[i][j] = 0.f;

    for (int k0 = 0; k0 < KDIM; k0 += 16) {
        float4 av = make_float4(0.f, 0.f, 0.f, 0.f);
        if (!GATHER || aptr) av = *(const float4*)(aptr + k0);
        const float4 bv = *(const float4*)(bptr + (size_t)k0 * NCOL);

        __syncthreads();
        As[akq * 4 + 0][arow] = av.x;
        As[akq * 4 + 1][arow] = av.y;
        As[akq * 4 + 2][arow] = av.z;
        As[akq * 4 + 3][arow] = av.w;
        *(float4*)&Bs[bk][bcq * 4] = bv;
        __syncthreads();

#pragma unroll
        for (int k = 0; k < 16; ++k) {
            const float4 a = *(const float4*)&As[k][ty * 4];
            const float4 b = *(const float4*)&Bs[k][tx * 4];
            const float aa[4] = {a.x, a.y, a.z, a.w};
            const float bb[4] = {b.x, b.y, b.z, b.w};
#pragma unroll
            for (int i = 0; i < 4; ++i)
#pragma unroll
                for (int j = 0; j < 4; ++j)
                    acc[i][j] = fmaf(aa[i], bb[j], acc[i][j]);
        }
    }

    const float4 bv4 = *(const float4*)(ball + (size_t)e * NCOL + col0 + tx * 4);
    const float bb[4] = {bv4.x, bv4.y, bv4.z, bv4.w};

    if (FINAL) {
#pragma unroll
        for (int i = 0; i < 4; ++i) {
            const int slot = slot0 + ty * 4 + i;
            const int t = tok[slot];
            if (t < 0) continue;
            const float g = gat[slot];
            float* op = Out + (size_t)t * NCOL + col0 + tx * 4;
#pragma unroll
            for (int j = 0; j < 4; ++j) {
                const float v = fmaxf(acc[i][j] + bb[j], 0.f) * g;
                atomicAdd(op + j, v);
            }
        }
    } else {
#pragma unroll
        for (int i = 0; i < 4; ++i) {
            const int slot = slot0 + ty * 4 + i;
            float4 o;
            o.x = fmaxf(acc[i][0] + bb[0], 0.f);
            o.y = fmaxf(acc[i][1] + bb[1], 0.f);
            o.z = fmaxf(acc[i][2] + bb[2], 0.f);
            o.w = fmaxf(acc[i][3] + bb[3], 0.f);
            *(float4*)(Out + (size_t)slot * NCOL + col0 + tx * 4) = o;
        }
    }
}

extern "C" void kernel_launch(void* const* d_in, const int* in_sizes, int n_in,
                              void* d_out, int out_size, void* d_ws, size_t ws_size,
                              hipStream_t stream)
{
    const float* x  = (const float*)d_in[0];
    const float* Wg = (const float*)d_in[1];
    const float* bg = (const float*)d_in[2];
    const float* W1 = (const float*)d_in[3];
    const float* b1 = (const float*)d_in[4];
    const float* W2 = (const float*)d_in[5];
    const float* b2 = (const float*)d_in[6];
    const float* W3 = (const float*)d_in[7];
    const float* b3 = (const float*)d_in[8];
    float* out = (float*)d_out;

    char* ws = (char*)d_ws;
    int*   counts = (int*)(ws + CNT_OFF);
    int*   cursor = (int*)(ws + CUR_OFF);
    int*   toff   = (int*)(ws + TOFF_OFF);
    int*   top2e  = (int*)(ws + TOP2E_OFF);
    float* top2g  = (float*)(ws + TOP2G_OFF);
    int*   tok    = (int*)(ws + TOK_OFF);
    float* gat    = (float*)(ws + GAT_OFF);
    float* h1     = (float*)(ws + H1_OFF);
    float* h2     = (float*)(ws + H2_OFF);

    hipMemsetAsync(out, 0, sizeof(float) * (size_t)NTOK * DDIM, stream);
    hipMemsetAsync(counts, 0, 8 * sizeof(int), stream);
    hipMemsetAsync(tok, 0xFF, CAP * sizeof(int), stream);  // padding slots = -1

    gate_topk<<<NTOK / 4, 256, 0, stream>>>(x, Wg, bg, top2e, top2g, counts);
    make_offsets<<<1, 64, 0, stream>>>(counts, toff, cursor);
    scatter<<<NTOK / 256, 256, 0, stream>>>(top2e, top2g, toff, cursor, tok, gat);

    expert_gemm<DDIM, HDIM, true,  false><<<dim3(NTILES, HDIM / 64), 256, 0, stream>>>(
        x,  W1, b1, toff, tok, gat, h1);
    expert_gemm<HDIM, HDIM, false, false><<<dim3(NTILES, HDIM / 64), 256, 0, stream>>>(
        h1, W2, b2, toff, tok, gat, h2);
    expert_gemm<HDIM, DDIM, false, true ><<<dim3(NTILES, DDIM / 64), 256, 0, stream>>>(
        h2, W3, b3, toff, tok, gat, out);
}

// Round 2
// 355.438 us; speedup vs baseline: 2.0261x; 2.0261x over previous
//
#include <hip/hip_runtime.h>
#include <math.h>

// Problem constants
#define NTOK 8192
#define DDIM 1024
#define NEXP 8
#define HDIM 256
#define TOPK 2
#define PADM 128                         // per-expert row padding (tile height)
#define CAPS (NTOK * TOPK + NEXP * PADM) // 17408 slots max
#define NT128 (CAPS / 128)               // 136 row tiles

typedef __attribute__((ext_vector_type(8))) __bf16 bf16x8;
typedef __attribute__((ext_vector_type(4))) float f32x4;

#define GLDS16(g, s)                                                      \
    __builtin_amdgcn_global_load_lds(                                     \
        (const __attribute__((address_space(1))) void*)(g),               \
        (__attribute__((address_space(3))) void*)(s), 16, 0, 0)

// ---------------- workspace layout (bytes) ----------------
static constexpr size_t OFF_CNT  = 0;                                   // 8 int
static constexpr size_t OFF_CUR  = 64;                                  // 8 int
static constexpr size_t OFF_TOFF = 128;                                 // 9 int
static constexpr size_t OFF_ZBUF = 4096;                                // 4KB zeros
static constexpr size_t OFF_T2E  = 8192;                                // N*2 int
static constexpr size_t OFF_T2G  = OFF_T2E + (size_t)NTOK * TOPK * 4;   // N*2 f32
static constexpr size_t OFF_SLOT = OFF_T2G + (size_t)NTOK * TOPK * 4;   // N*2 int
static constexpr size_t OFF_TOK  = OFF_SLOT + (size_t)NTOK * TOPK * 4;  // CAPS int
static constexpr size_t OFF_GAT  = OFF_TOK + (size_t)CAPS * 4;          // CAPS f32
static constexpr size_t OFF_XB   = (OFF_GAT + (size_t)CAPS * 4 + 255) & ~(size_t)255;
static constexpr size_t OFF_W1T  = OFF_XB  + (size_t)NTOK * DDIM * 2;   // [E][H][D] bf16
static constexpr size_t OFF_W2T  = OFF_W1T + (size_t)NEXP * DDIM * HDIM * 2;
static constexpr size_t OFF_W3T  = OFF_W2T + (size_t)NEXP * HDIM * HDIM * 2;
static constexpr size_t OFF_H1   = OFF_W3T + (size_t)NEXP * HDIM * DDIM * 2;
static constexpr size_t OFF_H2   = OFF_H1  + (size_t)CAPS * HDIM * 2;
static constexpr size_t OFF_H3   = OFF_H2  + (size_t)CAPS * HDIM * 2;   // [CAPS][D] bf16

static __device__ __forceinline__ unsigned short f2b(float f) {
    __bf16 h = (__bf16)f;
    return __builtin_bit_cast(unsigned short, h);
}
static __device__ __forceinline__ float b2f(unsigned short u) {
    return __builtin_bit_cast(float, ((unsigned)u) << 16);
}

// ---------------------------------------------------------------------------
// x f32 -> bf16 (RNE), vectorized: float4 in, ushort4 out.
// ---------------------------------------------------------------------------
__global__ __launch_bounds__(256) void convert_x(
    const float* __restrict__ x, unsigned short* __restrict__ xb)
{
    const size_t i = ((size_t)blockIdx.x * 256 + threadIdx.x) * 4;
    const float4 v = *(const float4*)(x + i);
    ushort4 u;
    u.x = f2b(v.x); u.y = f2b(v.y); u.z = f2b(v.z); u.w = f2b(v.w);
    *(ushort4*)(xb + i) = u;
}

// ---------------------------------------------------------------------------
// W [E][R][C] f32  ->  Wt [E][C][R] bf16  (32x32 LDS tile transpose)
// ---------------------------------------------------------------------------
__global__ __launch_bounds__(256) void transpose_w(
    const float* __restrict__ Win, __bf16* __restrict__ Wout, int R, int C)
{
    __shared__ float t[32][33];
    const int e  = blockIdx.z;
    const int r0 = blockIdx.y * 32, c0 = blockIdx.x * 32;
    const int tx = threadIdx.x & 31, ty = threadIdx.x >> 5;  // 32 x 8
    const float* Wi = Win + (size_t)e * R * C;
    __bf16* Wo = Wout + (size_t)e * C * R;
#pragma unroll
    for (int j = 0; j < 4; ++j)
        t[ty + j * 8][tx] = Wi[(size_t)(r0 + ty + j * 8) * C + c0 + tx];
    __syncthreads();
#pragma unroll
    for (int j = 0; j < 4; ++j)
        Wo[(size_t)(c0 + ty + j * 8) * R + r0 + tx] = (__bf16)t[tx][ty + j * 8];
}

// ---------------------------------------------------------------------------
// Gating: one wave per token (as round 1, validated).
// ---------------------------------------------------------------------------
__global__ __launch_bounds__(256) void gate_topk(
    const float* __restrict__ x, const float* __restrict__ Wg,
    const float* __restrict__ bg, int* __restrict__ top2e,
    float* __restrict__ top2g, int* __restrict__ counts)
{
    const int n = blockIdx.x * 4 + (threadIdx.x >> 6);
    const int lane = threadIdx.x & 63;
    const float* xr = x + (size_t)n * DDIM;

    float acc[NEXP];
#pragma unroll
    for (int e = 0; e < NEXP; ++e) acc[e] = 0.f;

#pragma unroll 4
    for (int it = 0; it < DDIM / 64; ++it) {
        const int d = it * 64 + lane;
        const float xv = xr[d];
        const float* wr = Wg + (size_t)d * NEXP;
        const float4 w0 = *(const float4*)wr;
        const float4 w1 = *(const float4*)(wr + 4);
        acc[0] = fmaf(xv, w0.x, acc[0]); acc[1] = fmaf(xv, w0.y, acc[1]);
        acc[2] = fmaf(xv, w0.z, acc[2]); acc[3] = fmaf(xv, w0.w, acc[3]);
        acc[4] = fmaf(xv, w1.x, acc[4]); acc[5] = fmaf(xv, w1.y, acc[5]);
        acc[6] = fmaf(xv, w1.z, acc[6]); acc[7] = fmaf(xv, w1.w, acc[7]);
    }
#pragma unroll
    for (int off = 32; off > 0; off >>= 1)
#pragma unroll
        for (int e = 0; e < NEXP; ++e) acc[e] += __shfl_down(acc[e], off, 64);

    if (lane == 0) {
        float v[NEXP], mx = -1e30f;
#pragma unroll
        for (int e = 0; e < NEXP; ++e) { v[e] = acc[e] + bg[e]; mx = fmaxf(mx, v[e]); }
        float p[NEXP], s = 0.f;
#pragma unroll
        for (int e = 0; e < NEXP; ++e) { p[e] = expf(v[e] - mx); s += p[e]; }
        const float inv = 1.f / s;
#pragma unroll
        for (int e = 0; e < NEXP; ++e) p[e] *= inv;
        int i0 = 0;
#pragma unroll
        for (int e = 1; e < NEXP; ++e) if (p[e] > p[i0]) i0 = e;
        int i1 = (i0 == 0) ? 1 : 0;
#pragma unroll
        for (int e = 0; e < NEXP; ++e) if (e != i0 && p[e] > p[i1]) i1 = e;
        top2e[n * 2 + 0] = i0;  top2e[n * 2 + 1] = i1;
        top2g[n * 2 + 0] = p[i0]; top2g[n * 2 + 1] = p[i1];
        atomicAdd(&counts[i0], 1);
        atomicAdd(&counts[i1], 1);
    }
}

// Padded prefix sum: expert ranges 128-aligned so GEMM tiles never span experts.
__global__ void make_offsets(const int* __restrict__ counts,
                             int* __restrict__ toff, int* __restrict__ cursor)
{
    if (threadIdx.x == 0 && blockIdx.x == 0) {
        int acc = 0;
#pragma unroll
        for (int e = 0; e < NEXP; ++e) {
            toff[e] = acc;
            acc += (counts[e] + PADM - 1) & ~(PADM - 1);
            cursor[e] = 0;
        }
        toff[NEXP] = acc;
    }
}

__global__ __launch_bounds__(256) void scatter(
    const int* __restrict__ top2e, const float* __restrict__ top2g,
    const int* __restrict__ toff, int* __restrict__ cursor,
    int* __restrict__ tok, float* __restrict__ gat, int* __restrict__ slotof)
{
    const int n = blockIdx.x * blockDim.x + threadIdx.x;
    if (n >= NTOK) return;
#pragma unroll
    for (int k = 0; k < TOPK; ++k) {
        const int e = top2e[n * 2 + k];
        const int pos = atomicAdd(&cursor[e], 1);
        const int slot = toff[e] + pos;
        tok[slot] = n;
        gat[slot] = top2g[n * 2 + k];
        slotof[n * 2 + k] = slot;
    }
}

// ---------------------------------------------------------------------------
// Grouped bf16 MFMA GEMM. 128x128 tile, 4 waves x (64x64), BK=64.
// LDS tiles [128 rows][64 k] bf16 (128B rows), XOR-swizzled 16B slots:
// phys_slot = k_slot ^ (row&7). Staged via global_load_lds (linear LDS dest,
// inverse-swizzled per-lane GLOBAL source), read via swizzled ds_read_b128.
// GATHER: A rows gathered from xb via tok[] (pad rows -> zero page).
// FINAL : epilogue val = relu(acc+b)*gate, stored bf16 to h3[slot][NCOL].
// ---------------------------------------------------------------------------
template<int KDIM, int NCOL, bool GATHER, bool FINAL>
__global__ __launch_bounds__(256) void egemm(
    const __bf16* __restrict__ Ain, const __bf16* __restrict__ Wt,
    const float* __restrict__ ball, const int* __restrict__ toff,
    const int* __restrict__ tok, const float* __restrict__ gat,
    const char* __restrict__ zbuf, __bf16* __restrict__ Out)
{
    const int total = toff[NEXP];
    const int slot0 = blockIdx.x * 128;
    if (slot0 >= total) return;
    int e = 0;
    while (toff[e + 1] <= slot0) ++e;
    const int col0 = blockIdx.y * 128;

    __shared__ __align__(16) char smem[32768];
    char* AsB = smem;            // [128][64] bf16, swizzled
    char* BsB = smem + 16384;    // [128 n][64 k] bf16, swizzled

    const int tid  = threadIdx.x;
    const int lane = tid & 63;
    const int wid  = tid >> 6;
    const int wr = wid >> 1, wc = wid & 1;

    // ---- staging source pointers (per-lane global, inverse-swizzled) ----
    const int srow  = tid >> 3;   // 0..31 (+32 per iter)
    const int sslot = tid & 7;    // 16B slot within 128B row
    const __bf16* We = Wt + (size_t)e * NCOL * KDIM;
    const char* ap[4];
    const char* bp[4];
#pragma unroll
    for (int i = 0; i < 4; ++i) {
        const int row = i * 32 + srow;
        const int ks  = sslot ^ (row & 7);
        if (GATHER) {
            const int t = tok[slot0 + row];
            ap[i] = (t >= 0) ? (const char*)(Ain + (size_t)t * KDIM + ks * 8) : zbuf;
        } else {
            ap[i] = (const char*)(Ain + (size_t)(slot0 + row) * KDIM + ks * 8);
        }
        bp[i] = (const char*)(We + (size_t)(col0 + row) * KDIM + ks * 8);
    }

    // ---- fragment read offsets ----
    const int llo = lane & 15, lhi = lane >> 4;
    int abyte[4], am7[4], bbyte[4], bm7[4];
#pragma unroll
    for (int m = 0; m < 4; ++m) {
        const int r = wr * 64 + m * 16 + llo;
        abyte[m] = r * 128; am7[m] = r & 7;
        const int c = wc * 64 + m * 16 + llo;
        bbyte[m] = c * 128; bm7[m] = c & 7;
    }

    f32x4 acc[4][4];
#pragma unroll
    for (int m = 0; m < 4; ++m)
#pragma unroll
        for (int n = 0; n < 4; ++n) acc[m][n] = (f32x4){0.f, 0.f, 0.f, 0.f};

    for (int k0 = 0; k0 < KDIM; k0 += 64) {
        const size_t kb = (size_t)k0 * 2;
#pragma unroll
        for (int i = 0; i < 4; ++i)
            GLDS16(ap[i] + kb, AsB + i * 4096 + wid * 1024);
#pragma unroll
        for (int i = 0; i < 4; ++i)
            GLDS16(bp[i] + kb, BsB + i * 4096 + wid * 1024);
        __syncthreads();
#pragma unroll
        for (int kk = 0; kk < 2; ++kk) {
            bf16x8 af[4], bfr[4];
#pragma unroll
            for (int m = 0; m < 4; ++m)
                af[m] = *(const bf16x8*)(AsB + abyte[m] + ((((kk << 2) + lhi) ^ am7[m]) << 4));
#pragma unroll
            for (int n = 0; n < 4; ++n)
                bfr[n] = *(const bf16x8*)(BsB + bbyte[n] + ((((kk << 2) + lhi) ^ bm7[n]) << 4));
#pragma unroll
            for (int m = 0; m < 4; ++m)
#pragma unroll
                for (int n = 0; n < 4; ++n)
                    acc[m][n] = __builtin_amdgcn_mfma_f32_16x16x32_bf16(
                        af[m], bfr[n], acc[m][n], 0, 0, 0);
        }
        __syncthreads();
    }

    // ---- epilogue: C/D mapping col=lane&15, row=(lane>>4)*4+j ----
    const float* be = ball + (size_t)e * NCOL;
#pragma unroll
    for (int m = 0; m < 4; ++m) {
        const int rbase = slot0 + wr * 64 + m * 16 + lhi * 4;
        float g[4];
        if (FINAL) {
#pragma unroll
            for (int j = 0; j < 4; ++j) g[j] = gat[rbase + j];
        }
#pragma unroll
        for (int n = 0; n < 4; ++n) {
            const int col = col0 + wc * 64 + n * 16 + llo;
            const float bb = be[col];
#pragma unroll
            for (int j = 0; j < 4; ++j) {
                float v = fmaxf(acc[m][n][j] + bb, 0.f);
                if (FINAL) v *= g[j];
                Out[(size_t)(rbase + j) * NCOL + col] = (__bf16)v;
            }
        }
    }
}

// ---------------------------------------------------------------------------
// Combine: out[n][d] = h3[s0][d] + h3[s1][d]  (gates already applied in L3).
// ---------------------------------------------------------------------------
__global__ __launch_bounds__(256) void combine(
    const unsigned short* __restrict__ h3, const int* __restrict__ slotof,
    float* __restrict__ out)
{
    const int n = blockIdx.x;
    const int c = threadIdx.x * 4;
    const int s0 = slotof[n * 2], s1 = slotof[n * 2 + 1];
    const ushort4 a = *(const ushort4*)(h3 + (size_t)s0 * DDIM + c);
    const ushort4 b = *(const ushort4*)(h3 + (size_t)s1 * DDIM + c);
    float4 o;
    o.x = b2f(a.x) + b2f(b.x);
    o.y = b2f(a.y) + b2f(b.y);
    o.z = b2f(a.z) + b2f(b.z);
    o.w = b2f(a.w) + b2f(b.w);
    *(float4*)(out + (size_t)n * DDIM + c) = o;
}

extern "C" void kernel_launch(void* const* d_in, const int* in_sizes, int n_in,
                              void* d_out, int out_size, void* d_ws, size_t ws_size,
                              hipStream_t stream)
{
    const float* x  = (const float*)d_in[0];
    const float* Wg = (const float*)d_in[1];
    const float* bg = (const float*)d_in[2];
    const float* W1 = (const float*)d_in[3];
    const float* b1 = (const float*)d_in[4];
    const float* W2 = (const float*)d_in[5];
    const float* b2 = (const float*)d_in[6];
    const float* W3 = (const float*)d_in[7];
    const float* b3 = (const float*)d_in[8];
    float* out = (float*)d_out;

    char* ws = (char*)d_ws;
    int*   counts = (int*)(ws + OFF_CNT);
    int*   cursor = (int*)(ws + OFF_CUR);
    int*   toff   = (int*)(ws + OFF_TOFF);
    char*  zbuf   = ws + OFF_ZBUF;
    int*   top2e  = (int*)(ws + OFF_T2E);
    float* top2g  = (float*)(ws + OFF_T2G);
    int*   slotof = (int*)(ws + OFF_SLOT);
    int*   tok    = (int*)(ws + OFF_TOK);
    float* gat    = (float*)(ws + OFF_GAT);
    unsigned short* xbu = (unsigned short*)(ws + OFF_XB);
    __bf16* xb  = (__bf16*)(ws + OFF_XB);
    __bf16* w1t = (__bf16*)(ws + OFF_W1T);
    __bf16* w2t = (__bf16*)(ws + OFF_W2T);
    __bf16* w3t = (__bf16*)(ws + OFF_W3T);
    __bf16* h1  = (__bf16*)(ws + OFF_H1);
    __bf16* h2  = (__bf16*)(ws + OFF_H2);
    __bf16* h3  = (__bf16*)(ws + OFF_H3);

    hipMemsetAsync(counts, 0, 64, stream);
    hipMemsetAsync(zbuf, 0, 4096, stream);
    hipMemsetAsync(tok, 0xFF, (size_t)CAPS * 4, stream);

    // preprocessing (independent of gating)
    convert_x<<<NTOK * DDIM / 1024, 256, 0, stream>>>(x, xbu);
    transpose_w<<<dim3(HDIM / 32, DDIM / 32, NEXP), 256, 0, stream>>>(W1, w1t, DDIM, HDIM);
    transpose_w<<<dim3(HDIM / 32, HDIM / 32, NEXP), 256, 0, stream>>>(W2, w2t, HDIM, HDIM);
    transpose_w<<<dim3(DDIM / 32, HDIM / 32, NEXP), 256, 0, stream>>>(W3, w3t, HDIM, DDIM);

    // routing
    gate_topk<<<NTOK / 4, 256, 0, stream>>>(x, Wg, bg, top2e, top2g, counts);
    make_offsets<<<1, 64, 0, stream>>>(counts, toff, cursor);
    scatter<<<NTOK / 256, 256, 0, stream>>>(top2e, top2g, toff, cursor, tok, gat, slotof);

    // expert MLP (bf16 MFMA)
    egemm<DDIM, HDIM, true,  false><<<dim3(NT128, HDIM / 128), 256, 0, stream>>>(
        xb, w1t, b1, toff, tok, gat, zbuf, h1);
    egemm<HDIM, HDIM, false, false><<<dim3(NT128, HDIM / 128), 256, 0, stream>>>(
        h1, w2t, b2, toff, tok, gat, zbuf, h2);
    egemm<HDIM, DDIM, false, true ><<<dim3(NT128, DDIM / 128), 256, 0, stream>>>(
        h2, w3t, b3, toff, tok, gat, zbuf, h3);

    // combine the two expert contributions per token
    combine<<<NTOK, 256, 0, stream>>>((const unsigned short*)h3, slotof, out);
}

// Round 3
// 126.493 us; speedup vs baseline: 5.6932x; 2.8099x over previous
//
#include <hip/hip_runtime.h>
#include <math.h>

// Problem constants
#define NTOK 8192
#define DDIM 1024
#define NEXP 8
#define HDIM 256
#define TOPK 2
#define PADM 128                         // per-expert row padding (tile height)
#define CAPS (NTOK * TOPK + NEXP * PADM) // 17408 slots max
#define NT128 (CAPS / 128)               // 136 row tiles

typedef __attribute__((ext_vector_type(8))) __bf16 bf16x8;
typedef __attribute__((ext_vector_type(4))) float f32x4;

#define GLDS16(g, s)                                                      \
    __builtin_amdgcn_global_load_lds(                                     \
        (const __attribute__((address_space(1))) void*)(g),               \
        (__attribute__((address_space(3))) void*)(s), 16, 0, 0)

// ---------------- workspace layout (bytes) ----------------
static constexpr size_t OFF_TOFF = 128;                                 // 9 int
static constexpr size_t OFF_ZBUF = 4096;                                // 4KB zeros
static constexpr size_t OFF_T2E  = 8192;                                // N*2 int
static constexpr size_t OFF_T2G  = OFF_T2E + (size_t)NTOK * TOPK * 4;   // N*2 f32
static constexpr size_t OFF_SLOT = OFF_T2G + (size_t)NTOK * TOPK * 4;   // N*2 int
static constexpr size_t OFF_TOK  = OFF_SLOT + (size_t)NTOK * TOPK * 4;  // CAPS int
static constexpr size_t OFF_GAT  = OFF_TOK + (size_t)CAPS * 4;          // CAPS f32
static constexpr size_t OFF_XB   = (OFF_GAT + (size_t)CAPS * 4 + 255) & ~(size_t)255;
static constexpr size_t OFF_W1T  = OFF_XB  + (size_t)NTOK * DDIM * 2;   // [E][H][D] bf16
static constexpr size_t OFF_W2T  = OFF_W1T + (size_t)NEXP * DDIM * HDIM * 2;
static constexpr size_t OFF_W3T  = OFF_W2T + (size_t)NEXP * HDIM * HDIM * 2;
static constexpr size_t OFF_H1   = OFF_W3T + (size_t)NEXP * HDIM * DDIM * 2;
static constexpr size_t OFF_H2   = OFF_H1  + (size_t)CAPS * HDIM * 2;
static constexpr size_t OFF_H3   = OFF_H2  + (size_t)CAPS * HDIM * 2;   // [CAPS][D] bf16

static __device__ __forceinline__ unsigned short f2b(float f) {
    __bf16 h = (__bf16)f;
    return __builtin_bit_cast(unsigned short, h);
}
static __device__ __forceinline__ float b2f(unsigned short u) {
    return __builtin_bit_cast(float, ((unsigned)u) << 16);
}

// ---------------------------------------------------------------------------
// x f32 -> bf16 (RNE), vectorized: float4 in, ushort4 out.
// ---------------------------------------------------------------------------
__global__ __launch_bounds__(256) void convert_x(
    const float* __restrict__ x, unsigned short* __restrict__ xb)
{
    const size_t i = ((size_t)blockIdx.x * 256 + threadIdx.x) * 4;
    const float4 v = *(const float4*)(x + i);
    ushort4 u;
    u.x = f2b(v.x); u.y = f2b(v.y); u.z = f2b(v.z); u.w = f2b(v.w);
    *(ushort4*)(xb + i) = u;
}

// ---------------------------------------------------------------------------
// W [E][R][C] f32  ->  Wt [E][C][R] bf16  (32x32 LDS tile transpose)
// ---------------------------------------------------------------------------
__global__ __launch_bounds__(256) void transpose_w(
    const float* __restrict__ Win, __bf16* __restrict__ Wout, int R, int C)
{
    __shared__ float t[32][33];
    const int e  = blockIdx.z;
    const int r0 = blockIdx.y * 32, c0 = blockIdx.x * 32;
    const int tx = threadIdx.x & 31, ty = threadIdx.x >> 5;  // 32 x 8
    const float* Wi = Win + (size_t)e * R * C;
    __bf16* Wo = Wout + (size_t)e * C * R;
#pragma unroll
    for (int j = 0; j < 4; ++j)
        t[ty + j * 8][tx] = Wi[(size_t)(r0 + ty + j * 8) * C + c0 + tx];
    __syncthreads();
#pragma unroll
    for (int j = 0; j < 4; ++j)
        Wo[(size_t)(c0 + ty + j * 8) * R + r0 + tx] = (__bf16)t[tx][ty + j * 8];
}

// ---------------------------------------------------------------------------
// Gating: one wave per token. NO global atomics (they queue-drained ~195us).
// ---------------------------------------------------------------------------
__global__ __launch_bounds__(256) void gate_topk(
    const float* __restrict__ x, const float* __restrict__ Wg,
    const float* __restrict__ bg, int* __restrict__ top2e,
    float* __restrict__ top2g)
{
    const int n = blockIdx.x * 4 + (threadIdx.x >> 6);
    const int lane = threadIdx.x & 63;
    const float* xr = x + (size_t)n * DDIM;

    float acc[NEXP];
#pragma unroll
    for (int e = 0; e < NEXP; ++e) acc[e] = 0.f;

#pragma unroll 4
    for (int it = 0; it < DDIM / 64; ++it) {
        const int d = it * 64 + lane;
        const float xv = xr[d];
        const float* wr = Wg + (size_t)d * NEXP;
        const float4 w0 = *(const float4*)wr;
        const float4 w1 = *(const float4*)(wr + 4);
        acc[0] = fmaf(xv, w0.x, acc[0]); acc[1] = fmaf(xv, w0.y, acc[1]);
        acc[2] = fmaf(xv, w0.z, acc[2]); acc[3] = fmaf(xv, w0.w, acc[3]);
        acc[4] = fmaf(xv, w1.x, acc[4]); acc[5] = fmaf(xv, w1.y, acc[5]);
        acc[6] = fmaf(xv, w1.z, acc[6]); acc[7] = fmaf(xv, w1.w, acc[7]);
    }
#pragma unroll
    for (int off = 32; off > 0; off >>= 1)
#pragma unroll
        for (int e = 0; e < NEXP; ++e) acc[e] += __shfl_down(acc[e], off, 64);

    if (lane == 0) {
        float v[NEXP], mx = -1e30f;
#pragma unroll
        for (int e = 0; e < NEXP; ++e) { v[e] = acc[e] + bg[e]; mx = fmaxf(mx, v[e]); }
        float p[NEXP], s = 0.f;
#pragma unroll
        for (int e = 0; e < NEXP; ++e) { p[e] = expf(v[e] - mx); s += p[e]; }
        const float inv = 1.f / s;
#pragma unroll
        for (int e = 0; e < NEXP; ++e) p[e] *= inv;
        int i0 = 0;
#pragma unroll
        for (int e = 1; e < NEXP; ++e) if (p[e] > p[i0]) i0 = e;
        int i1 = (i0 == 0) ? 1 : 0;
#pragma unroll
        for (int e = 0; e < NEXP; ++e) if (e != i0 && p[e] > p[i1]) i1 = e;
        top2e[n * 2 + 0] = i0;  top2e[n * 2 + 1] = i1;
        top2g[n * 2 + 0] = p[i0]; top2g[n * 2 + 1] = p[i1];
    }
}

// ---------------------------------------------------------------------------
// route: ONE block, 1024 threads. Each thread owns 16 of the 16384 (n,k)
// entries. Register per-expert counts + wave shfl-scan + LDS cross-wave scan
// give every entry a unique slot in its expert's 128-aligned range.
// Zero global atomics; fully deterministic. Replaces make_offsets + scatter.
// ---------------------------------------------------------------------------
__global__ __launch_bounds__(1024) void route(
    const int* __restrict__ top2e, const float* __restrict__ top2g,
    int* __restrict__ toff, int* __restrict__ tok, float* __restrict__ gat,
    int* __restrict__ slotof)
{
    const int tid = threadIdx.x;
    const int wv = tid >> 6, ln = tid & 63;
    __shared__ int   waveTot[16][NEXP];
    __shared__ int   waveBase[16][NEXP];
    __shared__ int   toffS[NEXP + 1];
    __shared__ short excS[1024][NEXP];   // wave-exclusive rank, 16KB

    int myE[16]; float myG[16];
    const int4*   pe = (const int4*)(top2e + tid * 16);
    const float4* pg = (const float4*)(top2g + tid * 16);
#pragma unroll
    for (int q = 0; q < 4; ++q) {
        const int4 v = pe[q];
        myE[q * 4 + 0] = v.x; myE[q * 4 + 1] = v.y;
        myE[q * 4 + 2] = v.z; myE[q * 4 + 3] = v.w;
        const float4 g = pg[q];
        myG[q * 4 + 0] = g.x; myG[q * 4 + 1] = g.y;
        myG[q * 4 + 2] = g.z; myG[q * 4 + 3] = g.w;
    }

#pragma unroll
    for (int e = 0; e < NEXP; ++e) {
        int c = 0;
#pragma unroll
        for (int j = 0; j < 16; ++j) c += (myE[j] == e);
        int inc = c;
#pragma unroll
        for (int off = 1; off < 64; off <<= 1) {
            const int t = __shfl_up(inc, off, 64);
            if (ln >= off) inc += t;
        }
        excS[tid][e] = (short)(inc - c);
        if (ln == 63) waveTot[wv][e] = inc;
    }
    __syncthreads();

    if (tid < NEXP) {          // tid = expert id
        int b = 0;
#pragma unroll
        for (int w = 0; w < 16; ++w) {
            const int t = waveTot[w][tid];
            waveBase[w][tid] = b;
            b += t;
        }
        waveTot[0][tid] = b;   // expert total (waveTot no longer needed)
    }
    __syncthreads();

    if (tid == 0) {
        int acc = 0;
#pragma unroll
        for (int e = 0; e < NEXP; ++e) {
            toffS[e] = acc;
            acc += (waveTot[0][e] + PADM - 1) & ~(PADM - 1);
        }
        toffS[NEXP] = acc;
#pragma unroll
        for (int e = 0; e <= NEXP; ++e) toff[e] = toffS[e];
    }
    __syncthreads();

#pragma unroll
    for (int j = 0; j < 16; ++j) {
        int pre = 0;
#pragma unroll
        for (int j2 = 0; j2 < j; ++j2) pre += (myE[j2] == myE[j]);
        const int e = myE[j];
        const int slot = toffS[e] + waveBase[wv][e] + (int)excS[tid][e] + pre;
        const int i = tid * 16 + j;
        tok[slot] = i >> 1;
        gat[slot] = myG[j];
        slotof[i] = slot;
    }
}

// ---------------------------------------------------------------------------
// Grouped bf16 MFMA GEMM. 128x128 tile, 4 waves x (64x64), BK=64.
// LDS tiles [128 rows][64 k] bf16, XOR-swizzled 16B slots (both-sides).
// ---------------------------------------------------------------------------
template<int KDIM, int NCOL, bool GATHER, bool FINAL>
__global__ __launch_bounds__(256) void egemm(
    const __bf16* __restrict__ Ain, const __bf16* __restrict__ Wt,
    const float* __restrict__ ball, const int* __restrict__ toff,
    const int* __restrict__ tok, const float* __restrict__ gat,
    const char* __restrict__ zbuf, __bf16* __restrict__ Out)
{
    const int total = toff[NEXP];
    const int slot0 = blockIdx.x * 128;
    if (slot0 >= total) return;
    int e = 0;
    while (toff[e + 1] <= slot0) ++e;
    const int col0 = blockIdx.y * 128;

    __shared__ __align__(16) char smem[32768];
    char* AsB = smem;            // [128][64] bf16, swizzled
    char* BsB = smem + 16384;    // [128 n][64 k] bf16, swizzled

    const int tid  = threadIdx.x;
    const int lane = tid & 63;
    const int wid  = tid >> 6;
    const int wr = wid >> 1, wc = wid & 1;

    const int srow  = tid >> 3;   // 0..31 (+32 per iter)
    const int sslot = tid & 7;    // 16B slot within 128B row
    const __bf16* We = Wt + (size_t)e * NCOL * KDIM;
    const char* ap[4];
    const char* bp[4];
#pragma unroll
    for (int i = 0; i < 4; ++i) {
        const int row = i * 32 + srow;
        const int ks  = sslot ^ (row & 7);
        if (GATHER) {
            const int t = tok[slot0 + row];
            ap[i] = (t >= 0) ? (const char*)(Ain + (size_t)t * KDIM + ks * 8) : zbuf;
        } else {
            ap[i] = (const char*)(Ain + (size_t)(slot0 + row) * KDIM + ks * 8);
        }
        bp[i] = (const char*)(We + (size_t)(col0 + row) * KDIM + ks * 8);
    }

    const int llo = lane & 15, lhi = lane >> 4;
    int abyte[4], am7[4], bbyte[4], bm7[4];
#pragma unroll
    for (int m = 0; m < 4; ++m) {
        const int r = wr * 64 + m * 16 + llo;
        abyte[m] = r * 128; am7[m] = r & 7;
        const int c = wc * 64 + m * 16 + llo;
        bbyte[m] = c * 128; bm7[m] = c & 7;
    }

    f32x4 acc[4][4];
#pragma unroll
    for (int m = 0; m < 4; ++m)
#pragma unroll
        for (int n = 0; n < 4; ++n) acc[m][n] = (f32x4){0.f, 0.f, 0.f, 0.f};

    for (int k0 = 0; k0 < KDIM; k0 += 64) {
        const size_t kb = (size_t)k0 * 2;
#pragma unroll
        for (int i = 0; i < 4; ++i)
            GLDS16(ap[i] + kb, AsB + i * 4096 + wid * 1024);
#pragma unroll
        for (int i = 0; i < 4; ++i)
            GLDS16(bp[i] + kb, BsB + i * 4096 + wid * 1024);
        __syncthreads();
#pragma unroll
        for (int kk = 0; kk < 2; ++kk) {
            bf16x8 af[4], bfr[4];
#pragma unroll
            for (int m = 0; m < 4; ++m)
                af[m] = *(const bf16x8*)(AsB + abyte[m] + ((((kk << 2) + lhi) ^ am7[m]) << 4));
#pragma unroll
            for (int n = 0; n < 4; ++n)
                bfr[n] = *(const bf16x8*)(BsB + bbyte[n] + ((((kk << 2) + lhi) ^ bm7[n]) << 4));
#pragma unroll
            for (int m = 0; m < 4; ++m)
#pragma unroll
                for (int n = 0; n < 4; ++n)
                    acc[m][n] = __builtin_amdgcn_mfma_f32_16x16x32_bf16(
                        af[m], bfr[n], acc[m][n], 0, 0, 0);
        }
        __syncthreads();
    }

    const float* be = ball + (size_t)e * NCOL;
#pragma unroll
    for (int m = 0; m < 4; ++m) {
        const int rbase = slot0 + wr * 64 + m * 16 + lhi * 4;
        float g[4];
        if (FINAL) {
#pragma unroll
            for (int j = 0; j < 4; ++j) g[j] = gat[rbase + j];
        }
#pragma unroll
        for (int n = 0; n < 4; ++n) {
            const int col = col0 + wc * 64 + n * 16 + llo;
            const float bb = be[col];
#pragma unroll
            for (int j = 0; j < 4; ++j) {
                float v = fmaxf(acc[m][n][j] + bb, 0.f);
                if (FINAL) v *= g[j];
                Out[(size_t)(rbase + j) * NCOL + col] = (__bf16)v;
            }
        }
    }
}

// ---------------------------------------------------------------------------
// Combine: out[n][d] = h3[s0][d] + h3[s1][d]  (gates already applied in L3).
// ---------------------------------------------------------------------------
__global__ __launch_bounds__(256) void combine(
    const unsigned short* __restrict__ h3, const int* __restrict__ slotof,
    float* __restrict__ out)
{
    const int n = blockIdx.x;
    const int c = threadIdx.x * 4;
    const int s0 = slotof[n * 2], s1 = slotof[n * 2 + 1];
    const ushort4 a = *(const ushort4*)(h3 + (size_t)s0 * DDIM + c);
    const ushort4 b = *(const ushort4*)(h3 + (size_t)s1 * DDIM + c);
    float4 o;
    o.x = b2f(a.x) + b2f(b.x);
    o.y = b2f(a.y) + b2f(b.y);
    o.z = b2f(a.z) + b2f(b.z);
    o.w = b2f(a.w) + b2f(b.w);
    *(float4*)(out + (size_t)n * DDIM + c) = o;
}

extern "C" void kernel_launch(void* const* d_in, const int* in_sizes, int n_in,
                              void* d_out, int out_size, void* d_ws, size_t ws_size,
                              hipStream_t stream)
{
    const float* x  = (const float*)d_in[0];
    const float* Wg = (const float*)d_in[1];
    const float* bg = (const float*)d_in[2];
    const float* W1 = (const float*)d_in[3];
    const float* b1 = (const float*)d_in[4];
    const float* W2 = (const float*)d_in[5];
    const float* b2 = (const float*)d_in[6];
    const float* W3 = (const float*)d_in[7];
    const float* b3 = (const float*)d_in[8];
    float* out = (float*)d_out;

    char* ws = (char*)d_ws;
    int*   toff   = (int*)(ws + OFF_TOFF);
    char*  zbuf   = ws + OFF_ZBUF;
    int*   top2e  = (int*)(ws + OFF_T2E);
    float* top2g  = (float*)(ws + OFF_T2G);
    int*   slotof = (int*)(ws + OFF_SLOT);
    int*   tok    = (int*)(ws + OFF_TOK);
    float* gat    = (float*)(ws + OFF_GAT);
    unsigned short* xbu = (unsigned short*)(ws + OFF_XB);
    __bf16* xb  = (__bf16*)(ws + OFF_XB);
    __bf16* w1t = (__bf16*)(ws + OFF_W1T);
    __bf16* w2t = (__bf16*)(ws + OFF_W2T);
    __bf16* w3t = (__bf16*)(ws + OFF_W3T);
    __bf16* h1  = (__bf16*)(ws + OFF_H1);
    __bf16* h2  = (__bf16*)(ws + OFF_H2);
    __bf16* h3  = (__bf16*)(ws + OFF_H3);

    hipMemsetAsync(zbuf, 0, 4096, stream);
    hipMemsetAsync(tok, 0xFF, (size_t)CAPS * 4, stream);

    // preprocessing (independent of gating)
    convert_x<<<NTOK * DDIM / 1024, 256, 0, stream>>>(x, xbu);
    transpose_w<<<dim3(HDIM / 32, DDIM / 32, NEXP), 256, 0, stream>>>(W1, w1t, DDIM, HDIM);
    transpose_w<<<dim3(HDIM / 32, HDIM / 32, NEXP), 256, 0, stream>>>(W2, w2t, HDIM, HDIM);
    transpose_w<<<dim3(DDIM / 32, HDIM / 32, NEXP), 256, 0, stream>>>(W3, w3t, HDIM, DDIM);

    // routing (no contended atomics anywhere)
    gate_topk<<<NTOK / 4, 256, 0, stream>>>(x, Wg, bg, top2e, top2g);
    route<<<1, 1024, 0, stream>>>(top2e, top2g, toff, tok, gat, slotof);

    // expert MLP (bf16 MFMA)
    egemm<DDIM, HDIM, true,  false><<<dim3(NT128, HDIM / 128), 256, 0, stream>>>(
        xb, w1t, b1, toff, tok, gat, zbuf, h1);
    egemm<HDIM, HDIM, false, false><<<dim3(NT128, HDIM / 128), 256, 0, stream>>>(
        h1, w2t, b2, toff, tok, gat, zbuf, h2);
    egemm<HDIM, DDIM, false, true ><<<dim3(NT128, DDIM / 128), 256, 0, stream>>>(
        h2, w3t, b3, toff, tok, gat, zbuf, h3);

    // combine the two expert contributions per token
    combine<<<NTOK, 256, 0, stream>>>((const unsigned short*)h3, slotof, out);
}

// Round 4
// 120.479 us; speedup vs baseline: 5.9773x; 1.0499x over previous
//
#include <hip/hip_runtime.h>
#include <math.h>

// Problem constants
#define NTOK 8192
#define DDIM 1024
#define NEXP 8
#define HDIM 256
#define TOPK 2
#define PADM 128                         // per-expert row padding (tile height)
#define CAPS (NTOK * TOPK + NEXP * PADM) // 17408 slots max
#define NT128 (CAPS / 128)               // 136 row tiles

typedef __attribute__((ext_vector_type(8))) __bf16 bf16x8;
typedef __attribute__((ext_vector_type(4))) float f32x4;

#define GLDS16(g, s)                                                      \
    __builtin_amdgcn_global_load_lds(                                     \
        (const __attribute__((address_space(1))) void*)(g),               \
        (__attribute__((address_space(3))) void*)(s), 16, 0, 0)

// ---------------- workspace layout (bytes) ----------------
static constexpr size_t OFF_TOFF = 128;                                 // 9 int
static constexpr size_t OFF_ZBUF = 4096;                                // 4KB zeros
static constexpr size_t OFF_T2E  = 8192;                                // N*2 int
static constexpr size_t OFF_T2G  = OFF_T2E + (size_t)NTOK * TOPK * 4;   // N*2 f32
static constexpr size_t OFF_SLOT = OFF_T2G + (size_t)NTOK * TOPK * 4;   // N*2 int
static constexpr size_t OFF_TOK  = OFF_SLOT + (size_t)NTOK * TOPK * 4;  // CAPS int
static constexpr size_t OFF_GAT  = OFF_TOK + (size_t)CAPS * 4;          // CAPS f32
static constexpr size_t OFF_XB   = (OFF_GAT + (size_t)CAPS * 4 + 255) & ~(size_t)255;
static constexpr size_t OFF_W1T  = OFF_XB  + (size_t)NTOK * DDIM * 2;   // [E][H][D] bf16
static constexpr size_t OFF_W2T  = OFF_W1T + (size_t)NEXP * DDIM * HDIM * 2;
static constexpr size_t OFF_W3T  = OFF_W2T + (size_t)NEXP * HDIM * HDIM * 2;
static constexpr size_t OFF_H1   = OFF_W3T + (size_t)NEXP * HDIM * DDIM * 2;
static constexpr size_t OFF_H2   = OFF_H1  + (size_t)CAPS * HDIM * 2;
static constexpr size_t OFF_H3   = OFF_H2  + (size_t)CAPS * HDIM * 2;   // [CAPS][D] bf16

static __device__ __forceinline__ unsigned short f2b(float f) {
    __bf16 h = (__bf16)f;
    return __builtin_bit_cast(unsigned short, h);
}
static __device__ __forceinline__ float b2f(unsigned short u) {
    return __builtin_bit_cast(float, ((unsigned)u) << 16);
}

// ---------------------------------------------------------------------------
// x f32 -> bf16 (RNE), vectorized: float4 in, ushort4 out.
// ---------------------------------------------------------------------------
__global__ __launch_bounds__(256) void convert_x(
    const float* __restrict__ x, unsigned short* __restrict__ xb)
{
    const size_t i = ((size_t)blockIdx.x * 256 + threadIdx.x) * 4;
    const float4 v = *(const float4*)(x + i);
    ushort4 u;
    u.x = f2b(v.x); u.y = f2b(v.y); u.z = f2b(v.z); u.w = f2b(v.w);
    *(ushort4*)(xb + i) = u;
}

// ---------------------------------------------------------------------------
// W [E][R][C] f32  ->  Wt [E][C][R] bf16  (32x32 LDS tile transpose)
// ---------------------------------------------------------------------------
__global__ __launch_bounds__(256) void transpose_w(
    const float* __restrict__ Win, __bf16* __restrict__ Wout, int R, int C)
{
    __shared__ float t[32][33];
    const int e  = blockIdx.z;
    const int r0 = blockIdx.y * 32, c0 = blockIdx.x * 32;
    const int tx = threadIdx.x & 31, ty = threadIdx.x >> 5;  // 32 x 8
    const float* Wi = Win + (size_t)e * R * C;
    __bf16* Wo = Wout + (size_t)e * C * R;
#pragma unroll
    for (int j = 0; j < 4; ++j)
        t[ty + j * 8][tx] = Wi[(size_t)(r0 + ty + j * 8) * C + c0 + tx];
    __syncthreads();
#pragma unroll
    for (int j = 0; j < 4; ++j)
        Wo[(size_t)(c0 + ty + j * 8) * R + r0 + tx] = (__bf16)t[tx][ty + j * 8];
}

// ---------------------------------------------------------------------------
// Gating: one wave per token. No global atomics.
// ---------------------------------------------------------------------------
__global__ __launch_bounds__(256) void gate_topk(
    const float* __restrict__ x, const float* __restrict__ Wg,
    const float* __restrict__ bg, int* __restrict__ top2e,
    float* __restrict__ top2g)
{
    const int n = blockIdx.x * 4 + (threadIdx.x >> 6);
    const int lane = threadIdx.x & 63;
    const float* xr = x + (size_t)n * DDIM;

    float acc[NEXP];
#pragma unroll
    for (int e = 0; e < NEXP; ++e) acc[e] = 0.f;

#pragma unroll 4
    for (int it = 0; it < DDIM / 64; ++it) {
        const int d = it * 64 + lane;
        const float xv = xr[d];
        const float* wr = Wg + (size_t)d * NEXP;
        const float4 w0 = *(const float4*)wr;
        const float4 w1 = *(const float4*)(wr + 4);
        acc[0] = fmaf(xv, w0.x, acc[0]); acc[1] = fmaf(xv, w0.y, acc[1]);
        acc[2] = fmaf(xv, w0.z, acc[2]); acc[3] = fmaf(xv, w0.w, acc[3]);
        acc[4] = fmaf(xv, w1.x, acc[4]); acc[5] = fmaf(xv, w1.y, acc[5]);
        acc[6] = fmaf(xv, w1.z, acc[6]); acc[7] = fmaf(xv, w1.w, acc[7]);
    }
#pragma unroll
    for (int off = 32; off > 0; off >>= 1)
#pragma unroll
        for (int e = 0; e < NEXP; ++e) acc[e] += __shfl_down(acc[e], off, 64);

    if (lane == 0) {
        float v[NEXP], mx = -1e30f;
#pragma unroll
        for (int e = 0; e < NEXP; ++e) { v[e] = acc[e] + bg[e]; mx = fmaxf(mx, v[e]); }
        float p[NEXP], s = 0.f;
#pragma unroll
        for (int e = 0; e < NEXP; ++e) { p[e] = expf(v[e] - mx); s += p[e]; }
        const float inv = 1.f / s;
#pragma unroll
        for (int e = 0; e < NEXP; ++e) p[e] *= inv;
        int i0 = 0;
#pragma unroll
        for (int e = 1; e < NEXP; ++e) if (p[e] > p[i0]) i0 = e;
        int i1 = (i0 == 0) ? 1 : 0;
#pragma unroll
        for (int e = 0; e < NEXP; ++e) if (e != i0 && p[e] > p[i1]) i1 = e;
        top2e[n * 2 + 0] = i0;  top2e[n * 2 + 1] = i1;
        top2g[n * 2 + 0] = p[i0]; top2g[n * 2 + 1] = p[i1];
    }
}

// ---------------------------------------------------------------------------
// route: ONE block, 1024 threads. Each thread owns 16 of the 16384 (n,k)
// entries. Register per-expert counts + wave shfl-scan + LDS cross-wave scan
// give every entry a unique slot in its expert's 128-aligned range.
// Also fills padding slots (tok=-1, gat=0) and zeros zbuf — this replaces the
// in-graph hipMemsetAsync calls, which cost ~40us EACH as rocclr fill
// dispatches (R3 profile: 68KB fill = 40us).
// ---------------------------------------------------------------------------
__global__ __launch_bounds__(1024) void route(
    const int* __restrict__ top2e, const float* __restrict__ top2g,
    int* __restrict__ toff, int* __restrict__ tok, float* __restrict__ gat,
    int* __restrict__ slotof, float* __restrict__ zbuf)
{
    const int tid = threadIdx.x;
    const int wv = tid >> 6, ln = tid & 63;
    __shared__ int   waveTot[16][NEXP];
    __shared__ int   waveBase[16][NEXP];
    __shared__ int   totS[NEXP];
    __shared__ int   toffS[NEXP + 1];
    __shared__ short excS[1024][NEXP];   // wave-exclusive rank, 16KB

    zbuf[tid] = 0.f;                     // 4KB zero page for pad-row gathers

    int myE[16]; float myG[16];
    const int4*   pe = (const int4*)(top2e + tid * 16);
    const float4* pg = (const float4*)(top2g + tid * 16);
#pragma unroll
    for (int q = 0; q < 4; ++q) {
        const int4 v = pe[q];
        myE[q * 4 + 0] = v.x; myE[q * 4 + 1] = v.y;
        myE[q * 4 + 2] = v.z; myE[q * 4 + 3] = v.w;
        const float4 g = pg[q];
        myG[q * 4 + 0] = g.x; myG[q * 4 + 1] = g.y;
        myG[q * 4 + 2] = g.z; myG[q * 4 + 3] = g.w;
    }

#pragma unroll
    for (int e = 0; e < NEXP; ++e) {
        int c = 0;
#pragma unroll
        for (int j = 0; j < 16; ++j) c += (myE[j] == e);
        int inc = c;
#pragma unroll
        for (int off = 1; off < 64; off <<= 1) {
            const int t = __shfl_up(inc, off, 64);
            if (ln >= off) inc += t;
        }
        excS[tid][e] = (short)(inc - c);
        if (ln == 63) waveTot[wv][e] = inc;
    }
    __syncthreads();

    if (tid < NEXP) {          // tid = expert id
        int b = 0;
#pragma unroll
        for (int w = 0; w < 16; ++w) {
            const int t = waveTot[w][tid];
            waveBase[w][tid] = b;
            b += t;
        }
        totS[tid] = b;
    }
    __syncthreads();

    if (tid == 0) {
        int acc = 0;
#pragma unroll
        for (int e = 0; e < NEXP; ++e) {
            toffS[e] = acc;
            acc += (totS[e] + PADM - 1) & ~(PADM - 1);
        }
        toffS[NEXP] = acc;
#pragma unroll
        for (int e = 0; e <= NEXP; ++e) toff[e] = toffS[e];
    }
    __syncthreads();

    // scatter entries to slots
#pragma unroll
    for (int j = 0; j < 16; ++j) {
        int pre = 0;
#pragma unroll
        for (int j2 = 0; j2 < j; ++j2) pre += (myE[j2] == myE[j]);
        const int e = myE[j];
        const int slot = toffS[e] + waveBase[wv][e] + (int)excS[tid][e] + pre;
        const int i = tid * 16 + j;
        tok[slot] = i >> 1;
        gat[slot] = myG[j];
        slotof[i] = slot;
    }

    // fill padding slots (<=127 per expert): tok=-1 -> zero-page gather; gat=0.
#pragma unroll
    for (int e = 0; e < NEXP; ++e) {
        const int begin = toffS[e] + totS[e];
        const int end   = toffS[e + 1];
        for (int i = begin + tid; i < end; i += 1024) {
            tok[i] = -1;
            gat[i] = 0.f;
        }
    }
}

// ---------------------------------------------------------------------------
// Grouped bf16 MFMA GEMM. 128x128 tile, 4 waves x (64x64), BK=64.
// LDS tiles [128 rows][64 k] bf16, XOR-swizzled 16B slots (both-sides).
// ---------------------------------------------------------------------------
template<int KDIM, int NCOL, bool GATHER, bool FINAL>
__global__ __launch_bounds__(256) void egemm(
    const __bf16* __restrict__ Ain, const __bf16* __restrict__ Wt,
    const float* __restrict__ ball, const int* __restrict__ toff,
    const int* __restrict__ tok, const float* __restrict__ gat,
    const char* __restrict__ zbuf, __bf16* __restrict__ Out)
{
    const int total = toff[NEXP];
    const int slot0 = blockIdx.x * 128;
    if (slot0 >= total) return;
    int e = 0;
    while (toff[e + 1] <= slot0) ++e;
    const int col0 = blockIdx.y * 128;

    __shared__ __align__(16) char smem[32768];
    char* AsB = smem;            // [128][64] bf16, swizzled
    char* BsB = smem + 16384;    // [128 n][64 k] bf16, swizzled

    const int tid  = threadIdx.x;
    const int lane = tid & 63;
    const int wid  = tid >> 6;
    const int wr = wid >> 1, wc = wid & 1;

    const int srow  = tid >> 3;   // 0..31 (+32 per iter)
    const int sslot = tid & 7;    // 16B slot within 128B row
    const __bf16* We = Wt + (size_t)e * NCOL * KDIM;
    const char* ap[4];
    const char* bp[4];
#pragma unroll
    for (int i = 0; i < 4; ++i) {
        const int row = i * 32 + srow;
        const int ks  = sslot ^ (row & 7);
        if (GATHER) {
            const int t = tok[slot0 + row];
            ap[i] = (t >= 0) ? (const char*)(Ain + (size_t)t * KDIM + ks * 8) : zbuf;
        } else {
            ap[i] = (const char*)(Ain + (size_t)(slot0 + row) * KDIM + ks * 8);
        }
        bp[i] = (const char*)(We + (size_t)(col0 + row) * KDIM + ks * 8);
    }

    const int llo = lane & 15, lhi = lane >> 4;
    int abyte[4], am7[4], bbyte[4], bm7[4];
#pragma unroll
    for (int m = 0; m < 4; ++m) {
        const int r = wr * 64 + m * 16 + llo;
        abyte[m] = r * 128; am7[m] = r & 7;
        const int c = wc * 64 + m * 16 + llo;
        bbyte[m] = c * 128; bm7[m] = c & 7;
    }

    f32x4 acc[4][4];
#pragma unroll
    for (int m = 0; m < 4; ++m)
#pragma unroll
        for (int n = 0; n < 4; ++n) acc[m][n] = (f32x4){0.f, 0.f, 0.f, 0.f};

    for (int k0 = 0; k0 < KDIM; k0 += 64) {
        const size_t kb = (size_t)k0 * 2;
#pragma unroll
        for (int i = 0; i < 4; ++i)
            GLDS16(ap[i] + kb, AsB + i * 4096 + wid * 1024);
#pragma unroll
        for (int i = 0; i < 4; ++i)
            GLDS16(bp[i] + kb, BsB + i * 4096 + wid * 1024);
        __syncthreads();
#pragma unroll
        for (int kk = 0; kk < 2; ++kk) {
            bf16x8 af[4], bfr[4];
#pragma unroll
            for (int m = 0; m < 4; ++m)
                af[m] = *(const bf16x8*)(AsB + abyte[m] + ((((kk << 2) + lhi) ^ am7[m]) << 4));
#pragma unroll
            for (int n = 0; n < 4; ++n)
                bfr[n] = *(const bf16x8*)(BsB + bbyte[n] + ((((kk << 2) + lhi) ^ bm7[n]) << 4));
#pragma unroll
            for (int m = 0; m < 4; ++m)
#pragma unroll
                for (int n = 0; n < 4; ++n)
                    acc[m][n] = __builtin_amdgcn_mfma_f32_16x16x32_bf16(
                        af[m], bfr[n], acc[m][n], 0, 0, 0);
        }
        __syncthreads();
    }

    const float* be = ball + (size_t)e * NCOL;
#pragma unroll
    for (int m = 0; m < 4; ++m) {
        const int rbase = slot0 + wr * 64 + m * 16 + lhi * 4;
        float g[4];
        if (FINAL) {
#pragma unroll
            for (int j = 0; j < 4; ++j) g[j] = gat[rbase + j];
        }
#pragma unroll
        for (int n = 0; n < 4; ++n) {
            const int col = col0 + wc * 64 + n * 16 + llo;
            const float bb = be[col];
#pragma unroll
            for (int j = 0; j < 4; ++j) {
                float v = fmaxf(acc[m][n][j] + bb, 0.f);
                if (FINAL) v *= g[j];
                Out[(size_t)(rbase + j) * NCOL + col] = (__bf16)v;
            }
        }
    }
}

// ---------------------------------------------------------------------------
// Combine: out[n][d] = h3[s0][d] + h3[s1][d]  (gates already applied in L3).
// ---------------------------------------------------------------------------
__global__ __launch_bounds__(256) void combine(
    const unsigned short* __restrict__ h3, const int* __restrict__ slotof,
    float* __restrict__ out)
{
    const int n = blockIdx.x;
    const int c = threadIdx.x * 4;
    const int s0 = slotof[n * 2], s1 = slotof[n * 2 + 1];
    const ushort4 a = *(const ushort4*)(h3 + (size_t)s0 * DDIM + c);
    const ushort4 b = *(const ushort4*)(h3 + (size_t)s1 * DDIM + c);
    float4 o;
    o.x = b2f(a.x) + b2f(b.x);
    o.y = b2f(a.y) + b2f(b.y);
    o.z = b2f(a.z) + b2f(b.z);
    o.w = b2f(a.w) + b2f(b.w);
    *(float4*)(out + (size_t)n * DDIM + c) = o;
}

extern "C" void kernel_launch(void* const* d_in, const int* in_sizes, int n_in,
                              void* d_out, int out_size, void* d_ws, size_t ws_size,
                              hipStream_t stream)
{
    const float* x  = (const float*)d_in[0];
    const float* Wg = (const float*)d_in[1];
    const float* bg = (const float*)d_in[2];
    const float* W1 = (const float*)d_in[3];
    const float* b1 = (const float*)d_in[4];
    const float* W2 = (const float*)d_in[5];
    const float* b2 = (const float*)d_in[6];
    const float* W3 = (const float*)d_in[7];
    const float* b3 = (const float*)d_in[8];
    float* out = (float*)d_out;

    char* ws = (char*)d_ws;
    int*   toff   = (int*)(ws + OFF_TOFF);
    char*  zbuf   = ws + OFF_ZBUF;
    int*   top2e  = (int*)(ws + OFF_T2E);
    float* top2g  = (float*)(ws + OFF_T2G);
    int*   slotof = (int*)(ws + OFF_SLOT);
    int*   tok    = (int*)(ws + OFF_TOK);
    float* gat    = (float*)(ws + OFF_GAT);
    unsigned short* xbu = (unsigned short*)(ws + OFF_XB);
    __bf16* xb  = (__bf16*)(ws + OFF_XB);
    __bf16* w1t = (__bf16*)(ws + OFF_W1T);
    __bf16* w2t = (__bf16*)(ws + OFF_W2T);
    __bf16* w3t = (__bf16*)(ws + OFF_W3T);
    __bf16* h1  = (__bf16*)(ws + OFF_H1);
    __bf16* h2  = (__bf16*)(ws + OFF_H2);
    __bf16* h3  = (__bf16*)(ws + OFF_H3);

    // preprocessing (independent of gating)
    convert_x<<<NTOK * DDIM / 1024, 256, 0, stream>>>(x, xbu);
    transpose_w<<<dim3(HDIM / 32, DDIM / 32, NEXP), 256, 0, stream>>>(W1, w1t, DDIM, HDIM);
    transpose_w<<<dim3(HDIM / 32, HDIM / 32, NEXP), 256, 0, stream>>>(W2, w2t, HDIM, HDIM);
    transpose_w<<<dim3(DDIM / 32, HDIM / 32, NEXP), 256, 0, stream>>>(W3, w3t, HDIM, DDIM);

    // routing (no contended atomics, no memsets — route does init itself)
    gate_topk<<<NTOK / 4, 256, 0, stream>>>(x, Wg, bg, top2e, top2g);
    route<<<1, 1024, 0, stream>>>(top2e, top2g, toff, tok, gat, slotof, (float*)zbuf);

    // expert MLP (bf16 MFMA)
    egemm<DDIM, HDIM, true,  false><<<dim3(NT128, HDIM / 128), 256, 0, stream>>>(
        xb, w1t, b1, toff, tok, gat, zbuf, h1);
    egemm<HDIM, HDIM, false, false><<<dim3(NT128, HDIM / 128), 256, 0, stream>>>(
        h1, w2t, b2, toff, tok, gat, zbuf, h2);
    egemm<HDIM, DDIM, false, true ><<<dim3(NT128, DDIM / 128), 256, 0, stream>>>(
        h2, w3t, b3, toff, tok, gat, zbuf, h3);

    // combine the two expert contributions per token
    combine<<<NTOK, 256, 0, stream>>>((const unsigned short*)h3, slotof, out);
}